// Round 3
// baseline (171.581 us; speedup 1.0000x reference)
//
#include <hip/hip_runtime.h>

#define Wd 640
#define Hd 512
#define NB 32
#define TW 64
#define TH 16
#define RR 4
constexpr int TILES_X = Wd / TW;   // 10
constexpr int TILES_Y = Hd / TH;   // 32
constexpr float EPSC = 0.5f;

// ---------------- Kernel A: disparity warp (bilinear along x) ----------------
__global__ __launch_bounds__(256)
void warp_kernel(const float* __restrict__ disp, const float* __restrict__ pattern,
                 float* __restrict__ proj)
{
    int gid = blockIdx.x * 256 + threadIdx.x;   // one thread per 4 px
    int n = gid * 4;
    float4 d4 = *(const float4*)(disp + n);
    int u = n % Wd;                             // W divisible by 4 -> same row
    int rowbase = ((n / Wd) % Hd) * Wd;
    float dv[4] = {d4.x, d4.y, d4.z, d4.w};
    #pragma unroll
    for (int j = 0; j < 4; ++j) {
        float x = (float)(u + j) - dv[j];
        x = fminf(fmaxf(x, 0.f), (float)(Wd - 1));
        float x0 = floorf(x);
        float w = x - x0;
        int i0 = (int)x0;
        int i1 = min(i0 + 1, Wd - 1);
        float g0 = pattern[rowbase + i0];
        float g1 = pattern[rowbase + i1];
        proj[n + j] = fmaf(w, g1 - g0, g0);
    }
}

// ---------------- census term: |c(da) - c(db)| with ONE rcp ----------------
// c(x) = x/(eps+|x|)
// ca - cb = [eps*(da-db) + (da*|db| - db*|da|)] / ((eps+|da|)*(eps+|db|))
__device__ __forceinline__ float census_term(float na, float nb, float ac, float bc)
{
    float da = na - ac;
    float db = nb - bc;
    float q  = fmaf(da, fabsf(db), -db * fabsf(da));     // da*|db| - db*|da|
    float num = fmaf(EPSC, da - db, q);
    float den = (EPSC + fabsf(da)) * (EPSC + fabsf(db)); // >= 0.25, rcp safe
    return fabsf(num) * __builtin_amdgcn_rcpf(den);
}

// ---- straight-line term expansion: ALL array indices are literal constants ----
// dh = 0 (right half-row): neighbors from a8/b8
#define T0(jj,dd) acc += census_term(a8[(jj)+(dd)], b8[(jj)+(dd)], a8[jj], b8[jj]);
#define ROW0_ALL \
  T0(0,1) T0(0,2) T0(0,3) T0(0,4) \
  T0(1,1) T0(1,2) T0(1,3) T0(1,4) \
  T0(2,1) T0(2,2) T0(2,3) T0(2,4) \
  T0(3,1) T0(3,2) T0(3,3) T0(3,4)

#define T0M(jj,dd) { float m = (ub+(jj)+(dd) < Wd) ? 1.f : 0.f; \
  acc = fmaf(m, census_term(a8[(jj)+(dd)], b8[(jj)+(dd)], a8[jj], b8[jj]), acc); }
#define ROW0_ALLM \
  T0M(0,1) T0M(0,2) T0M(0,3) T0M(0,4) \
  T0M(1,1) T0M(1,2) T0M(1,3) T0M(1,4) \
  T0M(2,1) T0M(2,2) T0M(2,3) T0M(2,4) \
  T0M(3,1) T0M(3,2) T0M(3,3) T0M(3,4)

// dh >= 1 rows: neighbors from ra/rb (cols u0-4 .. u0+7 => index j+dw+4 in [0,11])
#define TD(jj,dw) acc += census_term(ra[(jj)+(dw)+4], rb[(jj)+(dw)+4], a8[jj], b8[jj]);
#define ROWD(jj) TD(jj,-4) TD(jj,-3) TD(jj,-2) TD(jj,-1) TD(jj,0) TD(jj,1) TD(jj,2) TD(jj,3) TD(jj,4)
#define ROWD_ALL ROWD(0) ROWD(1) ROWD(2) ROWD(3)

#define TDM(jj,dw) { int uc = ub+(jj)+(dw); float m = (uc >= 0 && uc < Wd) ? mv : 0.f; \
  acc = fmaf(m, census_term(ra[(jj)+(dw)+4], rb[(jj)+(dw)+4], a8[jj], b8[jj]), acc); }
#define ROWDM(jj) TDM(jj,-4) TDM(jj,-3) TDM(jj,-2) TDM(jj,-1) TDM(jj,0) TDM(jj,1) TDM(jj,2) TDM(jj,3) TDM(jj,4)
#define ROWD_ALLM ROWDM(0) ROWDM(1) ROWDM(2) ROWDM(3)

// ---------------- Kernel B: half-space census sum over 64x16 tiles ----------------
__global__ __launch_bounds__(256, 4)
void census_kernel(const float* __restrict__ proj, const float* __restrict__ im,
                   float* __restrict__ partial)
{
    __shared__ float sa[TH + RR][TW + 2 * RR];  // 20 x 72 floats
    __shared__ float sb[TH + RR][TW + 2 * RR];

    const int tU = blockIdx.x, tV = blockIdx.y, b = blockIdx.z;
    const int tid = threadIdx.x;
    const float* pb = proj + (size_t)b * (Hd * Wd);
    const float* ib = im   + (size_t)b * (Hd * Wd);
    const int v0  = tV * TH;
    const int u0g = tU * TW - RR;               // global col of LDS col 0

    for (int idx = tid; idx < (TH + RR) * (TW + 2 * RR); idx += 256) {
        int r = idx / (TW + 2 * RR);
        int c = idx - r * (TW + 2 * RR);
        int gv = min(v0 + r, Hd - 1);           // only bottom halo (dh >= 0)
        int gu = min(max(u0g + c, 0), Wd - 1);  // clamp; masked in compute
        int off = gv * Wd + gu;
        sa[r][c] = pb[off];
        sb[r][c] = ib[off];
    }
    __syncthreads();

    const int ty = tid >> 4;                    // 0..15 (row in tile)
    const int tx = tid & 15;                    // 0..15 (group of 4 px)
    const int cu = RR + 4 * tx;                 // LDS col of px 0

    float a8[8], b8[8];                         // literal-filled, literal-indexed
    {
        float4 t;
        t = *(const float4*)&sa[ty][cu];     a8[0]=t.x; a8[1]=t.y; a8[2]=t.z; a8[3]=t.w;
        t = *(const float4*)&sa[ty][cu + 4]; a8[4]=t.x; a8[5]=t.y; a8[6]=t.z; a8[7]=t.w;
        t = *(const float4*)&sb[ty][cu];     b8[0]=t.x; b8[1]=t.y; b8[2]=t.z; b8[3]=t.w;
        t = *(const float4*)&sb[ty][cu + 4]; b8[4]=t.x; b8[5]=t.y; b8[6]=t.z; b8[7]=t.w;
    }

    float acc = 0.f;
    const bool edge = (tU == 0) | (tU == TILES_X - 1) | (tV == TILES_Y - 1);
    const int ub = tU * TW + 4 * tx;            // image col of px 0
    const int v  = v0 + ty;

    if (!edge) {
        ROW0_ALL
        for (int dh = 1; dh <= RR; ++dh) {      // runtime loop: only addresses vary
            float ra[12], rb[12];
            float4 t;
            t = *(const float4*)&sa[ty + dh][4 * tx];     ra[0]=t.x; ra[1]=t.y; ra[2]=t.z; ra[3]=t.w;
            t = *(const float4*)&sa[ty + dh][4 * tx + 4]; ra[4]=t.x; ra[5]=t.y; ra[6]=t.z; ra[7]=t.w;
            t = *(const float4*)&sa[ty + dh][4 * tx + 8]; ra[8]=t.x; ra[9]=t.y; ra[10]=t.z; ra[11]=t.w;
            t = *(const float4*)&sb[ty + dh][4 * tx];     rb[0]=t.x; rb[1]=t.y; rb[2]=t.z; rb[3]=t.w;
            t = *(const float4*)&sb[ty + dh][4 * tx + 4]; rb[4]=t.x; rb[5]=t.y; rb[6]=t.z; rb[7]=t.w;
            t = *(const float4*)&sb[ty + dh][4 * tx + 8]; rb[8]=t.x; rb[9]=t.y; rb[10]=t.z; rb[11]=t.w;
            ROWD_ALL
        }
    } else {
        ROW0_ALLM
        for (int dh = 1; dh <= RR; ++dh) {
            float ra[12], rb[12];
            float4 t;
            t = *(const float4*)&sa[ty + dh][4 * tx];     ra[0]=t.x; ra[1]=t.y; ra[2]=t.z; ra[3]=t.w;
            t = *(const float4*)&sa[ty + dh][4 * tx + 4]; ra[4]=t.x; ra[5]=t.y; ra[6]=t.z; ra[7]=t.w;
            t = *(const float4*)&sa[ty + dh][4 * tx + 8]; ra[8]=t.x; ra[9]=t.y; ra[10]=t.z; ra[11]=t.w;
            t = *(const float4*)&sb[ty + dh][4 * tx];     rb[0]=t.x; rb[1]=t.y; rb[2]=t.z; rb[3]=t.w;
            t = *(const float4*)&sb[ty + dh][4 * tx + 4]; rb[4]=t.x; rb[5]=t.y; rb[6]=t.z; rb[7]=t.w;
            t = *(const float4*)&sb[ty + dh][4 * tx + 8]; rb[8]=t.x; rb[9]=t.y; rb[10]=t.z; rb[11]=t.w;
            float mv = (v + dh < Hd) ? 1.f : 0.f;
            ROWD_ALLM
        }
    }

    // block reduction -> one partial per block (deterministic)
    #pragma unroll
    for (int o = 32; o; o >>= 1) acc += __shfl_down(acc, o);
    __shared__ float wsum[4];
    int wid = tid >> 6, lane = tid & 63;
    if (lane == 0) wsum[wid] = acc;
    __syncthreads();
    if (tid == 0) {
        float s = wsum[0] + wsum[1] + wsum[2] + wsum[3];
        partial[((int)blockIdx.z * gridDim.y + blockIdx.y) * gridDim.x + blockIdx.x] = s;
    }
}

// ---------------- Kernel C: final deterministic reduce ----------------
__global__ __launch_bounds__(1024)
void final_reduce(const float* __restrict__ partial, float* __restrict__ out)
{
    const int n = NB * TILES_Y * TILES_X;       // 10240
    double s = 0.0;
    for (int i = threadIdx.x; i < n; i += 1024) s += (double)partial[i];
    __shared__ double sm[1024];
    sm[threadIdx.x] = s;
    __syncthreads();
    for (int st = 512; st; st >>= 1) {
        if (threadIdx.x < st) sm[threadIdx.x] += sm[threadIdx.x + st];
        __syncthreads();
    }
    if (threadIdx.x == 0) {
        // val = 2 * S_half / (81 * B*H*W)   (half-space symmetry doubling)
        out[0] = (float)(sm[0] * (2.0 / (81.0 * (double)NB * Hd * Wd)));
    }
}

extern "C" void kernel_launch(void* const* d_in, const int* in_sizes, int n_in,
                              void* d_out, int out_size, void* d_ws, size_t ws_size,
                              hipStream_t stream)
{
    const float* disp    = (const float*)d_in[0];
    const float* im      = (const float*)d_in[1];
    const float* pattern = (const float*)d_in[2];
    float* out  = (float*)d_out;
    float* proj = out + 1;                      // output 1: pattern_proj
    float* partial = (float*)d_ws;              // 10240 floats scratch

    const int npx = NB * Hd * Wd;
    warp_kernel<<<npx / (256 * 4), 256, 0, stream>>>(disp, pattern, proj);

    dim3 grid(TILES_X, TILES_Y, NB);
    census_kernel<<<grid, 256, 0, stream>>>(proj, im, partial);

    final_reduce<<<1, 1024, 0, stream>>>(partial, out);
}

// Round 4
// 148.378 us; speedup vs baseline: 1.1564x; 1.1564x over previous
//
#include <hip/hip_runtime.h>

#define Wd 640
#define Hd 512
#define NB 32
#define TW 64
#define TH 16
#define RR 4
constexpr int TILES_X = Wd / TW;   // 10
constexpr int TILES_Y = Hd / TH;   // 32
constexpr float EPSC = 0.5f;

// ---------------- Kernel A: disparity warp (bilinear along x) ----------------
__global__ __launch_bounds__(256)
void warp_kernel(const float* __restrict__ disp, const float* __restrict__ pattern,
                 float* __restrict__ proj)
{
    int gid = blockIdx.x * 256 + threadIdx.x;   // one thread per 4 px
    int n = gid * 4;
    float4 d4 = *(const float4*)(disp + n);
    int u = n % Wd;                             // W divisible by 4 -> same row
    int rowbase = ((n / Wd) % Hd) * Wd;
    float dv[4] = {d4.x, d4.y, d4.z, d4.w};
    #pragma unroll
    for (int j = 0; j < 4; ++j) {
        float x = (float)(u + j) - dv[j];
        x = fminf(fmaxf(x, 0.f), (float)(Wd - 1));
        float x0 = floorf(x);
        float w = x - x0;
        int i0 = (int)x0;
        int i1 = min(i0 + 1, Wd - 1);
        float g0 = pattern[rowbase + i0];
        float g1 = pattern[rowbase + i1];
        proj[n + j] = fmaf(w, g1 - g0, g0);
    }
}

// ---------------- census numerator/denominator (d-form, no divide) ----------------
// c(x)=x/(eps+|x|);  ca-cb = (da*d2 - db*d1)/(d1*d2),  d1=eps+|da|, d2=eps+|db|
__device__ __forceinline__ void census_ne(float na, float nb, float ac, float bc,
                                          float& n, float& e)
{
    float da = na - ac;
    float db = nb - bc;
    float d1 = EPSC + fabsf(da);        // abs is a VOP3 modifier
    float d2 = EPSC + fabsf(db);
    n = fmaf(da, d2, -(db * d1));       // signed numerator
    e = d1 * d2;                        // in [0.25, ~2.25]
}

// Sum of 4 terms with ONE rcp: |n1|/e1+..+|n4|/e4 = (s12*e34+s34*e12)/(e12*e34)
__device__ __forceinline__ float comb4(float n1, float e1, float n2, float e2,
                                       float n3, float e3, float n4, float e4)
{
    float e12 = e1 * e2, e34 = e3 * e4;
    float s12 = fmaf(fabsf(n2), e1, fabsf(n1) * e2);
    float s34 = fmaf(fabsf(n4), e3, fabsf(n3) * e4);
    float t   = fmaf(s34, e12, s12 * e34);
    return t * __builtin_amdgcn_rcpf(e12 * e34);
}

// ---- group macros: 4 pixels (j=0..3) x one offset, literal indices ----
#define G0(d) { float n0,e0,n1,e1,n2,e2,n3,e3;                    \
  census_ne(a8[0+(d)], b8[0+(d)], a8[0], b8[0], n0, e0);          \
  census_ne(a8[1+(d)], b8[1+(d)], a8[1], b8[1], n1, e1);          \
  census_ne(a8[2+(d)], b8[2+(d)], a8[2], b8[2], n2, e2);          \
  census_ne(a8[3+(d)], b8[3+(d)], a8[3], b8[3], n3, e3);          \
  acc += comb4(n0,e0,n1,e1,n2,e2,n3,e3); }

#define G0M(d) { float n0,e0,n1,e1,n2,e2,n3,e3;                   \
  census_ne(a8[0+(d)], b8[0+(d)], a8[0], b8[0], n0, e0);          \
  census_ne(a8[1+(d)], b8[1+(d)], a8[1], b8[1], n1, e1);          \
  census_ne(a8[2+(d)], b8[2+(d)], a8[2], b8[2], n2, e2);          \
  census_ne(a8[3+(d)], b8[3+(d)], a8[3], b8[3], n3, e3);          \
  n0 *= (ub+0+(d) < Wd) ? 1.f : 0.f;                              \
  n1 *= (ub+1+(d) < Wd) ? 1.f : 0.f;                              \
  n2 *= (ub+2+(d) < Wd) ? 1.f : 0.f;                              \
  n3 *= (ub+3+(d) < Wd) ? 1.f : 0.f;                              \
  acc += comb4(n0,e0,n1,e1,n2,e2,n3,e3); }

#define GD(dw) { float n0,e0,n1,e1,n2,e2,n3,e3;                   \
  census_ne(ra[0+(dw)+4], rb[0+(dw)+4], a8[0], b8[0], n0, e0);    \
  census_ne(ra[1+(dw)+4], rb[1+(dw)+4], a8[1], b8[1], n1, e1);    \
  census_ne(ra[2+(dw)+4], rb[2+(dw)+4], a8[2], b8[2], n2, e2);    \
  census_ne(ra[3+(dw)+4], rb[3+(dw)+4], a8[3], b8[3], n3, e3);    \
  acc += comb4(n0,e0,n1,e1,n2,e2,n3,e3); }

#define GDM(dw) { float n0,e0,n1,e1,n2,e2,n3,e3;                  \
  census_ne(ra[0+(dw)+4], rb[0+(dw)+4], a8[0], b8[0], n0, e0);    \
  census_ne(ra[1+(dw)+4], rb[1+(dw)+4], a8[1], b8[1], n1, e1);    \
  census_ne(ra[2+(dw)+4], rb[2+(dw)+4], a8[2], b8[2], n2, e2);    \
  census_ne(ra[3+(dw)+4], rb[3+(dw)+4], a8[3], b8[3], n3, e3);    \
  { int u0c = ub+0+(dw); n0 *= (u0c >= 0 && u0c < Wd) ? mv : 0.f; } \
  { int u1c = ub+1+(dw); n1 *= (u1c >= 0 && u1c < Wd) ? mv : 0.f; } \
  { int u2c = ub+2+(dw); n2 *= (u2c >= 0 && u2c < Wd) ? mv : 0.f; } \
  { int u3c = ub+3+(dw); n3 *= (u3c >= 0 && u3c < Wd) ? mv : 0.f; } \
  acc += comb4(n0,e0,n1,e1,n2,e2,n3,e3); }

#define LOADROW(arr_a, arr_b, row)                                               \
  { float4 t;                                                                    \
    t = *(const float4*)&sa[row][4 * tx];     arr_a[0]=t.x; arr_a[1]=t.y; arr_a[2]=t.z; arr_a[3]=t.w; \
    t = *(const float4*)&sa[row][4 * tx + 4]; arr_a[4]=t.x; arr_a[5]=t.y; arr_a[6]=t.z; arr_a[7]=t.w; \
    t = *(const float4*)&sa[row][4 * tx + 8]; arr_a[8]=t.x; arr_a[9]=t.y; arr_a[10]=t.z; arr_a[11]=t.w; \
    t = *(const float4*)&sb[row][4 * tx];     arr_b[0]=t.x; arr_b[1]=t.y; arr_b[2]=t.z; arr_b[3]=t.w; \
    t = *(const float4*)&sb[row][4 * tx + 4]; arr_b[4]=t.x; arr_b[5]=t.y; arr_b[6]=t.z; arr_b[7]=t.w; \
    t = *(const float4*)&sb[row][4 * tx + 8]; arr_b[8]=t.x; arr_b[9]=t.y; arr_b[10]=t.z; arr_b[11]=t.w; }

// ---------------- Kernel B: half-space census sum over 64x16 tiles ----------------
__global__ __launch_bounds__(256)
void census_kernel(const float* __restrict__ proj, const float* __restrict__ im,
                   float* __restrict__ partial)
{
    __shared__ float sa[TH + RR][TW + 2 * RR];  // 20 x 72 floats
    __shared__ float sb[TH + RR][TW + 2 * RR];

    const int tU = blockIdx.x, tV = blockIdx.y, b = blockIdx.z;
    const int tid = threadIdx.x;
    const float* pb = proj + (size_t)b * (Hd * Wd);
    const float* ib = im   + (size_t)b * (Hd * Wd);
    const int v0  = tV * TH;
    const int u0g = tU * TW - RR;               // global col of LDS col 0

    for (int idx = tid; idx < (TH + RR) * (TW + 2 * RR); idx += 256) {
        int r = idx / (TW + 2 * RR);
        int c = idx - r * (TW + 2 * RR);
        int gv = min(v0 + r, Hd - 1);           // only bottom halo (dh >= 0)
        int gu = min(max(u0g + c, 0), Wd - 1);  // clamp; masked in compute
        int off = gv * Wd + gu;
        sa[r][c] = pb[off];
        sb[r][c] = ib[off];
    }
    __syncthreads();

    const int ty = tid >> 4;                    // 0..15 (row in tile)
    const int tx = tid & 15;                    // 0..15 (group of 4 px)
    const int cu = RR + 4 * tx;                 // LDS col of px 0

    float a8[8], b8[8];
    {
        float4 t;
        t = *(const float4*)&sa[ty][cu];     a8[0]=t.x; a8[1]=t.y; a8[2]=t.z; a8[3]=t.w;
        t = *(const float4*)&sa[ty][cu + 4]; a8[4]=t.x; a8[5]=t.y; a8[6]=t.z; a8[7]=t.w;
        t = *(const float4*)&sb[ty][cu];     b8[0]=t.x; b8[1]=t.y; b8[2]=t.z; b8[3]=t.w;
        t = *(const float4*)&sb[ty][cu + 4]; b8[4]=t.x; b8[5]=t.y; b8[6]=t.z; b8[7]=t.w;
    }

    float acc = 0.f;
    const bool edge = (tU == 0) | (tU == TILES_X - 1) | (tV == TILES_Y - 1);
    const int ub = tU * TW + 4 * tx;            // image col of px 0
    const int v  = v0 + ty;

    if (!edge) {
        G0(1) G0(2) G0(3) G0(4)
        for (int dh = 1; dh <= RR; ++dh) {      // runtime loop: only LDS addresses vary
            float ra[12], rb[12];
            LOADROW(ra, rb, ty + dh)
            GD(-4) GD(-3) GD(-2) GD(-1) GD(0) GD(1) GD(2) GD(3) GD(4)
        }
    } else {
        G0M(1) G0M(2) G0M(3) G0M(4)
        for (int dh = 1; dh <= RR; ++dh) {
            float ra[12], rb[12];
            LOADROW(ra, rb, ty + dh)
            float mv = (v + dh < Hd) ? 1.f : 0.f;
            GDM(-4) GDM(-3) GDM(-2) GDM(-1) GDM(0) GDM(1) GDM(2) GDM(3) GDM(4)
        }
    }

    // block reduction -> one partial per block (deterministic)
    #pragma unroll
    for (int o = 32; o; o >>= 1) acc += __shfl_down(acc, o);
    __shared__ float wsum[4];
    int wid = tid >> 6, lane = tid & 63;
    if (lane == 0) wsum[wid] = acc;
    __syncthreads();
    if (tid == 0) {
        float s = wsum[0] + wsum[1] + wsum[2] + wsum[3];
        partial[((int)blockIdx.z * gridDim.y + blockIdx.y) * gridDim.x + blockIdx.x] = s;
    }
}

// ---------------- Kernel C: final deterministic reduce ----------------
__global__ __launch_bounds__(1024)
void final_reduce(const float* __restrict__ partial, float* __restrict__ out)
{
    const int n = NB * TILES_Y * TILES_X;       // 10240
    double s = 0.0;
    for (int i = threadIdx.x; i < n; i += 1024) s += (double)partial[i];
    __shared__ double sm[1024];
    sm[threadIdx.x] = s;
    __syncthreads();
    for (int st = 512; st; st >>= 1) {
        if (threadIdx.x < st) sm[threadIdx.x] += sm[threadIdx.x + st];
        __syncthreads();
    }
    if (threadIdx.x == 0) {
        // val = 2 * S_half / (81 * B*H*W)   (half-space symmetry doubling)
        out[0] = (float)(sm[0] * (2.0 / (81.0 * (double)NB * Hd * Wd)));
    }
}

extern "C" void kernel_launch(void* const* d_in, const int* in_sizes, int n_in,
                              void* d_out, int out_size, void* d_ws, size_t ws_size,
                              hipStream_t stream)
{
    const float* disp    = (const float*)d_in[0];
    const float* im      = (const float*)d_in[1];
    const float* pattern = (const float*)d_in[2];
    float* out  = (float*)d_out;
    float* proj = out + 1;                      // output 1: pattern_proj
    float* partial = (float*)d_ws;              // 10240 floats scratch

    const int npx = NB * Hd * Wd;
    warp_kernel<<<npx / (256 * 4), 256, 0, stream>>>(disp, pattern, proj);

    dim3 grid(TILES_X, TILES_Y, NB);
    census_kernel<<<grid, 256, 0, stream>>>(proj, im, partial);

    final_reduce<<<1, 1024, 0, stream>>>(partial, out);
}

// Round 5
// 142.892 us; speedup vs baseline: 1.2008x; 1.0384x over previous
//
#include <hip/hip_runtime.h>

#define Wd 640
#define Hd 512
#define NB 32
#define TW 64
#define TH 16
#define RR 4
#define SW 76                      // padded LDS row stride (dwords): 19 blocks of 16B, 19%8=3
constexpr int TILES_X = Wd / TW;   // 10
constexpr int TILES_Y = Hd / TH;   // 32
constexpr float EPSC = 0.5f;

// ---------------- Kernel A: disparity warp (bilinear along x) ----------------
__global__ __launch_bounds__(256)
void warp_kernel(const float* __restrict__ disp, const float* __restrict__ pattern,
                 float* __restrict__ proj)
{
    int gid = blockIdx.x * 256 + threadIdx.x;   // one thread per 4 px
    int n = gid * 4;
    float4 d4 = *(const float4*)(disp + n);
    int u = n % Wd;
    int rowbase = ((n / Wd) % Hd) * Wd;
    float dv[4] = {d4.x, d4.y, d4.z, d4.w};
    #pragma unroll
    for (int j = 0; j < 4; ++j) {
        float x = (float)(u + j) - dv[j];
        x = fminf(fmaxf(x, 0.f), (float)(Wd - 1));
        float x0 = floorf(x);
        float w = x - x0;
        int i0 = (int)x0;
        int i1 = min(i0 + 1, Wd - 1);
        float g0 = pattern[rowbase + i0];
        float g1 = pattern[rowbase + i1];
        proj[n + j] = fmaf(w, g1 - g0, g0);
    }
}

// ---------------- census numerator/denominator (d-form, no divide) ----------------
// c(x)=x/(eps+|x|);  ca-cb = (da*d2 - db*d1)/(d1*d2),  d1=eps+|da|, d2=eps+|db|
__device__ __forceinline__ void census_ne(float na, float nb, float ac, float bc,
                                          float& n, float& e)
{
    float da = na - ac;
    float db = nb - bc;
    float d1 = EPSC + fabsf(da);
    float d2 = EPSC + fabsf(db);
    n = fmaf(da, d2, -(db * d1));
    e = d1 * d2;                        // in [0.25, 2.25]
}

// Sum of 4 terms with ONE rcp: |n1|/e1+..+|n4|/e4 = (s12*e34+s34*e12)/(e12*e34)
__device__ __forceinline__ float comb4(float n1, float e1, float n2, float e2,
                                       float n3, float e3, float n4, float e4)
{
    float e12 = e1 * e2, e34 = e3 * e4;
    float s12 = fmaf(fabsf(n2), e1, fabsf(n1) * e2);
    float s34 = fmaf(fabsf(n4), e3, fabsf(n3) * e4);
    float t   = fmaf(s34, e12, s12 * e34);
    return t * __builtin_amdgcn_rcpf(e12 * e34);
}

// ---- one group = 4 pixels x one offset; all operands are NAMED scalars ----
#define GRP4(ACC, xA0,xA1,xA2,xA3, xB0,xB1,xB2,xB3) { \
    float n0,e0,n1,e1,n2,e2,n3,e3;                    \
    census_ne(xA0,xB0,ca0,cb0,n0,e0);                 \
    census_ne(xA1,xB1,ca1,cb1,n1,e1);                 \
    census_ne(xA2,xB2,ca2,cb2,n2,e2);                 \
    census_ne(xA3,xB3,ca3,cb3,n3,e3);                 \
    ACC += comb4(n0,e0,n1,e1,n2,e2,n3,e3); }

#define GRPM(ACC, DW, xA0,xA1,xA2,xA3, xB0,xB1,xB2,xB3) { \
    float n0,e0,n1,e1,n2,e2,n3,e3;                    \
    census_ne(xA0,xB0,ca0,cb0,n0,e0);                 \
    census_ne(xA1,xB1,ca1,cb1,n1,e1);                 \
    census_ne(xA2,xB2,ca2,cb2,n2,e2);                 \
    census_ne(xA3,xB3,ca3,cb3,n3,e3);                 \
    n0 *= ((unsigned)(ub+0+(DW)) < (unsigned)Wd) ? mv : 0.f; \
    n1 *= ((unsigned)(ub+1+(DW)) < (unsigned)Wd) ? mv : 0.f; \
    n2 *= ((unsigned)(ub+2+(DW)) < (unsigned)Wd) ? mv : 0.f; \
    n3 *= ((unsigned)(ub+3+(DW)) < (unsigned)Wd) ? mv : 0.f; \
    ACC += comb4(n0,e0,n1,e1,n2,e2,n3,e3); }

// load a 12-float row window (cols 4tx .. 4tx+11) from both LDS tiles as named scalars
#define LOADROW(row)                                              \
    float4 tA0 = *(const float4*)&sa[row][4 * tx];                \
    float4 tA1 = *(const float4*)&sa[row][4 * tx + 4];            \
    float4 tA2 = *(const float4*)&sa[row][4 * tx + 8];            \
    float4 tB0 = *(const float4*)&sb[row][4 * tx];                \
    float4 tB1 = *(const float4*)&sb[row][4 * tx + 4];            \
    float4 tB2 = *(const float4*)&sb[row][4 * tx + 8];            \
    float ra0=tA0.x, ra1=tA0.y, ra2 =tA0.z, ra3 =tA0.w;           \
    float ra4=tA1.x, ra5=tA1.y, ra6 =tA1.z, ra7 =tA1.w;           \
    float ra8=tA2.x, ra9=tA2.y, ra10=tA2.z, ra11=tA2.w;           \
    float rb0=tB0.x, rb1=tB0.y, rb2 =tB0.z, rb3 =tB0.w;           \
    float rb4=tB1.x, rb5=tB1.y, rb6 =tB1.z, rb7 =tB1.w;           \
    float rb8=tB2.x, rb9=tB2.y, rb10=tB2.z, rb11=tB2.w;

#define NINE_GRPS(GM)                                             \
    GM(acc0, -4, ra0,ra1,ra2 ,ra3 , rb0,rb1,rb2 ,rb3 )            \
    GM(acc1, -3, ra1,ra2,ra3 ,ra4 , rb1,rb2,rb3 ,rb4 )            \
    GM(acc0, -2, ra2,ra3,ra4 ,ra5 , rb2,rb3,rb4 ,rb5 )            \
    GM(acc1, -1, ra3,ra4,ra5 ,ra6 , rb3,rb4,rb5 ,rb6 )            \
    GM(acc0,  0, ra4,ra5,ra6 ,ra7 , rb4,rb5,rb6 ,rb7 )            \
    GM(acc1,  1, ra5,ra6,ra7 ,ra8 , rb5,rb6,rb7 ,rb8 )            \
    GM(acc0,  2, ra6,ra7,ra8 ,ra9 , rb6,rb7,rb8 ,rb9 )            \
    GM(acc1,  3, ra7,ra8,ra9 ,ra10, rb7,rb8,rb9 ,rb10)            \
    GM(acc0,  4, ra8,ra9,ra10,ra11, rb8,rb9,rb10,rb11)

#define GRP4_NODW(ACC, DW, xA0,xA1,xA2,xA3, xB0,xB1,xB2,xB3) \
    GRP4(ACC, xA0,xA1,xA2,xA3, xB0,xB1,xB2,xB3)

// ---------------- Kernel B: half-space census sum over 64x16 tiles ----------------
__global__ __launch_bounds__(256)
void census_kernel(const float* __restrict__ proj, const float* __restrict__ im,
                   float* __restrict__ partial)
{
    __shared__ float sa[TH + RR][SW];   // 20 x 76 (cols 0..71 used)
    __shared__ float sb[TH + RR][SW];

    const int tU = blockIdx.x, tV = blockIdx.y, b = blockIdx.z;
    const int tid = threadIdx.x;
    const float* pb = proj + (size_t)b * (Hd * Wd);
    const float* ib = im   + (size_t)b * (Hd * Wd);
    const int v0  = tV * TH;
    const int u0g = tU * TW - RR;               // global col of LDS col 0

    const bool edge = (tU == 0) | (tU == TILES_X - 1) | (tV == TILES_Y - 1);

    if (!edge) {
        // fast staging: no clamps needed (rows v0..v0+19 <= 499, cols in range)
        const float* pbase = pb + v0 * Wd + u0g;
        const float* ibase = ib + v0 * Wd + u0g;
        for (int f = tid; f < (TH + RR) * (TW + 2 * RR) / 4; f += 256) { // 360 float4s
            int r = f / 18;
            int c = (f - 18 * r) * 4;
            *(float4*)&sa[r][c] = *(const float4*)(pbase + r * Wd + c);
            *(float4*)&sb[r][c] = *(const float4*)(ibase + r * Wd + c);
        }
    } else {
        for (int idx = tid; idx < (TH + RR) * (TW + 2 * RR); idx += 256) {
            int r = idx / (TW + 2 * RR);
            int c = idx - r * (TW + 2 * RR);
            int gv = min(v0 + r, Hd - 1);
            int gu = min(max(u0g + c, 0), Wd - 1);
            int off = gv * Wd + gu;
            sa[r][c] = pb[off];
            sb[r][c] = ib[off];
        }
    }
    __syncthreads();

    const int ty = tid >> 4;                    // 0..15 (row in tile)
    const int tx = tid & 15;                    // 0..15 (group of 4 px)

    float acc0 = 0.f, acc1 = 0.f;
    const int ub = tU * TW + 4 * tx;            // image col of px 0
    const int v  = v0 + ty;
    float ca0, ca1, ca2, ca3, cb0, cb1, cb2, cb3;

    if (!edge) {
        {   // center row: dh = 0, d = 1..4 (right half)
            LOADROW(ty)
            ca0 = ra4; ca1 = ra5; ca2 = ra6; ca3 = ra7;
            cb0 = rb4; cb1 = rb5; cb2 = rb6; cb3 = rb7;
            GRP4(acc0, ra5,ra6,ra7,ra8 , rb5,rb6,rb7,rb8 )
            GRP4(acc1, ra6,ra7,ra8,ra9 , rb6,rb7,rb8,rb9 )
            GRP4(acc0, ra7,ra8,ra9,ra10, rb7,rb8,rb9,rb10)
            GRP4(acc1, ra8,ra9,ra10,ra11, rb8,rb9,rb10,rb11)
        }
        for (int dh = 1; dh <= RR; ++dh) {
            LOADROW(ty + dh)
            NINE_GRPS(GRP4_NODW)
        }
    } else {
        {
            LOADROW(ty)
            ca0 = ra4; ca1 = ra5; ca2 = ra6; ca3 = ra7;
            cb0 = rb4; cb1 = rb5; cb2 = rb6; cb3 = rb7;
            float mv = 1.f;
            GRPM(acc0, 1, ra5,ra6,ra7,ra8 , rb5,rb6,rb7,rb8 )
            GRPM(acc1, 2, ra6,ra7,ra8,ra9 , rb6,rb7,rb8,rb9 )
            GRPM(acc0, 3, ra7,ra8,ra9,ra10, rb7,rb8,rb9,rb10)
            GRPM(acc1, 4, ra8,ra9,ra10,ra11, rb8,rb9,rb10,rb11)
        }
        for (int dh = 1; dh <= RR; ++dh) {
            LOADROW(ty + dh)
            float mv = (v + dh < Hd) ? 1.f : 0.f;
            NINE_GRPS(GRPM)
        }
    }

    float acc = acc0 + acc1;
    // block reduction -> one partial per block (deterministic)
    #pragma unroll
    for (int o = 32; o; o >>= 1) acc += __shfl_down(acc, o);
    __shared__ float wsum[4];
    int wid = tid >> 6, lane = tid & 63;
    if (lane == 0) wsum[wid] = acc;
    __syncthreads();
    if (tid == 0) {
        float s = wsum[0] + wsum[1] + wsum[2] + wsum[3];
        partial[((int)blockIdx.z * gridDim.y + blockIdx.y) * gridDim.x + blockIdx.x] = s;
    }
}

// ---------------- Kernel C: final deterministic reduce ----------------
__global__ __launch_bounds__(1024)
void final_reduce(const float* __restrict__ partial, float* __restrict__ out)
{
    const int n = NB * TILES_Y * TILES_X;       // 10240
    double s = 0.0;
    for (int i = threadIdx.x; i < n; i += 1024) s += (double)partial[i];
    __shared__ double sm[1024];
    sm[threadIdx.x] = s;
    __syncthreads();
    for (int st = 512; st; st >>= 1) {
        if (threadIdx.x < st) sm[threadIdx.x] += sm[threadIdx.x + st];
        __syncthreads();
    }
    if (threadIdx.x == 0) {
        // val = 2 * S_half / (81 * B*H*W)   (half-space symmetry doubling)
        out[0] = (float)(sm[0] * (2.0 / (81.0 * (double)NB * Hd * Wd)));
    }
}

extern "C" void kernel_launch(void* const* d_in, const int* in_sizes, int n_in,
                              void* d_out, int out_size, void* d_ws, size_t ws_size,
                              hipStream_t stream)
{
    const float* disp    = (const float*)d_in[0];
    const float* im      = (const float*)d_in[1];
    const float* pattern = (const float*)d_in[2];
    float* out  = (float*)d_out;
    float* proj = out + 1;                      // output 1: pattern_proj
    float* partial = (float*)d_ws;              // 10240 floats scratch

    const int npx = NB * Hd * Wd;
    warp_kernel<<<npx / (256 * 4), 256, 0, stream>>>(disp, pattern, proj);

    dim3 grid(TILES_X, TILES_Y, NB);
    census_kernel<<<grid, 256, 0, stream>>>(proj, im, partial);

    final_reduce<<<1, 1024, 0, stream>>>(partial, out);
}